// Round 4
// baseline (1562.066 us; speedup 1.0000x reference)
//
#include <hip/hip_runtime.h>
#include <math.h>

constexpr int N_NODES = 4096;
constexpr int N_EDGES = 65536;
constexpr int D_INF   = 64;
constexpr int H       = 128;
constexpr int T       = 8;
constexpr int B       = 8;
constexpr int M       = B * N_NODES;   // 32768 rows per GEMM

typedef __attribute__((ext_vector_type(8))) short bf16x8;
typedef __attribute__((ext_vector_type(4))) float f32x4;

__device__ inline unsigned short f2bf(float x) {
  unsigned int u = __float_as_uint(x);
  unsigned int r = (u + 0x7fffu + ((u >> 16) & 1u)) >> 16;
  return (unsigned short)r;
}
__device__ inline float bf2f(unsigned short b) {
  return __uint_as_float((unsigned int)b << 16);
}

// ---------------- CSR build ----------------

__global__ void k_count(const int* __restrict__ dst, int* __restrict__ cnt) {
  int e = blockIdx.x * blockDim.x + threadIdx.x;
  if (e < N_EDGES) atomicAdd(&cnt[dst[e]], 1);
}

__global__ void k_dinv(const int* __restrict__ cnt, float* __restrict__ dinv) {
  int n = blockIdx.x * blockDim.x + threadIdx.x;
  if (n < N_NODES) dinv[n] = 1.0f / sqrtf((float)cnt[n] + 2.0f);
}

__global__ void k_scan(const int* __restrict__ cnt, int* __restrict__ rowptr) {
  __shared__ int sums[1024];
  int t = threadIdx.x;
  int v0 = cnt[4*t+0], v1 = cnt[4*t+1], v2 = cnt[4*t+2], v3 = cnt[4*t+3];
  int s0 = v0, s1 = s0 + v1, s2 = s1 + v2, s3 = s2 + v3;
  sums[t] = s3;
  __syncthreads();
  for (int off = 1; off < 1024; off <<= 1) {
    int x = (t >= off) ? sums[t - off] : 0;
    __syncthreads();
    sums[t] += x;
    __syncthreads();
  }
  int base = (t > 0) ? sums[t - 1] : 0;
  if (t == 0) rowptr[0] = 0;
  rowptr[4*t+1] = base + s0;
  rowptr[4*t+2] = base + s1;
  rowptr[4*t+3] = base + s2;
  rowptr[4*t+4] = base + s3;
}

__global__ void k_fill(const int* __restrict__ src, const int* __restrict__ dst,
                       const float* __restrict__ dinv, const int* __restrict__ rowptr,
                       int* __restrict__ fill, int2* __restrict__ eg) {
  int e = blockIdx.x * blockDim.x + threadIdx.x;
  if (e >= N_EDGES) return;
  int s = src[e], d = dst[e];
  int p = rowptr[d] + atomicAdd(&fill[d], 1);
  eg[p] = make_int2(s, __float_as_int(dinv[s] * dinv[d]));
}

// ---------------- W pack: gate-interleaved cols + MFMA fragment order + hi/lo ----
__global__ void k_pack(const float* __restrict__ W, unsigned short* __restrict__ Bp,
                       int K) {
  int tid = blockIdx.x * 256 + threadIdx.x;
  if (tid >= K * 64) return;
  int lane = tid & 63;
  int ntg  = (tid >> 6) & 31;
  int kb   = tid >> 11;
  int gate = ntg & 3, fg = ntg >> 2;
  int corig = gate * 128 + fg * 16 + (lane & 15);
  int k0 = kb * 32 + (lane >> 4) * 8;
  long obase = ((long)(kb * 32 + ntg) * 64 + lane) * 8;
  long plane = (long)K * 512;
  #pragma unroll
  for (int j = 0; j < 8; ++j) {
    float v = W[(long)(k0 + j) * 512 + corig];
    unsigned short h = f2bf(v);
    Bp[obase + j]         = h;
    Bp[plane + obase + j] = f2bf(v - bf2f(h));
  }
}

// ---------------- phase-striped SpMM ----------------
// One pass gathers ONE source plane X (row width F) and writes stripe
// [C0, C0+F) of Ah/Al (row width Ktot). Wave = one (b,n) node, processes
// G = 64*4/F edges per iteration via lane groups; __shfl_xor group-reduce.
// XCD swizzle: batch b -> XCD b.
template<int F>
__global__ __launch_bounds__(256) void k_spmm2(
    const int* __restrict__ rowptr, const int2* __restrict__ eg,
    const float* __restrict__ dinv,
    const float* __restrict__ X, long bstride, int C0, int Ktot,
    unsigned short* __restrict__ Ah, unsigned short* __restrict__ Al) {
  constexpr int LPG = F / 4;        // lanes per edge group (16 or 32)
  constexpr int G   = 64 / LPG;     // edges per iteration (4 or 2)
  int tid  = threadIdx.x;
  int wid  = tid >> 6;
  int lane = tid & 63;
  int j    = blockIdx.x;                        // 8192 blocks
  int obk  = (j & 7) * 1024 + (j >> 3);         // XCD j%8 <-> batch
  int node = obk * 4 + wid;
  int b = node >> 12, n = node & (N_NODES - 1);
  int g  = lane / LPG;
  int l  = lane % LPG;
  int c4 = l * 4;
  const float* Xb = X + (long)b * bstride;
  f32x4 acc = {0.f, 0.f, 0.f, 0.f};
  int rs = rowptr[n], re = rowptr[n + 1];
  int e = rs + g;
  // unroll-by-2 over this group's edges for MLP
  for (; e + G < re; e += 2 * G) {
    int2 e0 = eg[e];
    int2 e1 = eg[e + G];
    f32x4 v0 = *(const f32x4*)(Xb + (long)e0.x * F + c4);
    f32x4 v1 = *(const f32x4*)(Xb + (long)e1.x * F + c4);
    acc += __int_as_float(e0.y) * v0;
    acc += __int_as_float(e1.y) * v1;
  }
  if (e < re) {
    int2 e0 = eg[e];
    f32x4 v0 = *(const f32x4*)(Xb + (long)e0.x * F + c4);
    acc += __int_as_float(e0.y) * v0;
  }
  // reduce across edge groups
  #pragma unroll
  for (int off = LPG; off < 64; off <<= 1) {
    acc[0] += __shfl_xor(acc[0], off, 64);
    acc[1] += __shfl_xor(acc[1], off, 64);
    acc[2] += __shfl_xor(acc[2], off, 64);
    acc[3] += __shfl_xor(acc[3], off, 64);
  }
  if (g == 0) {
    float dn = dinv[n];
    float sw = 2.0f * dn * dn;
    f32x4 v = *(const f32x4*)(Xb + (long)n * F + c4);
    acc += sw * v;
    unsigned short hs[4], ls[4];
    #pragma unroll
    for (int jj = 0; jj < 4; ++jj) {
      unsigned short h = f2bf(acc[jj]);
      hs[jj] = h;
      ls[jj] = f2bf(acc[jj] - bf2f(h));
    }
    uint2 hp, lp;
    hp.x = (unsigned)hs[0] | ((unsigned)hs[1] << 16);
    hp.y = (unsigned)hs[2] | ((unsigned)hs[3] << 16);
    lp.x = (unsigned)ls[0] | ((unsigned)ls[1] << 16);
    lp.y = (unsigned)ls[2] | ((unsigned)ls[3] << 16);
    *(uint2*)(Ah + (long)node * Ktot + C0 + c4) = hp;
    *(uint2*)(Al + (long)node * Ktot + C0 + c4) = lp;
  }
}

// ---------------- MFMA GEMM (split-bf16, 3-term) + fused LSTM ----------------
template<int K>
__global__ __launch_bounds__(256, 3) void k_gemm_lstm(
    const unsigned short* __restrict__ Ah, const unsigned short* __restrict__ Al,
    const unsigned short* __restrict__ Bp, const float* __restrict__ bias,
    float* __restrict__ hbuf, float* __restrict__ cbuf,
    float* __restrict__ out2, int t) {
  constexpr int KB = K / 32;
  __shared__ __align__(16) unsigned short At[4 * KB * 64 * 8];  // 24/32 KB
  int tid  = threadIdx.x;
  int j    = blockIdx.x;                          // 1024 blocks
  int mblk = (j & 7) * 128 + (j >> 3);            // XCD-align with producer batch
  int m0   = mblk * 32;
  int lane = tid & 63;
  int w    = tid >> 6;

  constexpr int NCH = 4 * KB * 64;
  #pragma unroll
  for (int it = 0; it < NCH / 256; ++it) {
    int chunk = it * 256 + tid;
    int cl = chunk & 63;
    int t1 = chunk >> 6;
    int kb = t1 % KB;
    int pm = t1 / KB;
    const unsigned short* sp = (pm >= 2 ? Al : Ah)
        + (long)(m0 + (pm & 1) * 16 + (cl & 15)) * K + kb * 32 + (cl >> 4) * 8;
    *(bf16x8*)(At + (long)chunk * 8) = *(const bf16x8*)sp;
  }
  __syncthreads();

  int fgb = w * 2;
  const unsigned short* bh = Bp + (long)(fgb * 4) * 512 + lane * 8;
  const unsigned short* bl = bh + (long)K * 512;

  f32x4 acc[2][2][4];
  #pragma unroll
  for (int ff = 0; ff < 2; ++ff)
    #pragma unroll
    for (int mt = 0; mt < 2; ++mt)
      #pragma unroll
      for (int gt = 0; gt < 4; ++gt)
        acc[ff][mt][gt] = (f32x4){0.f, 0.f, 0.f, 0.f};

  #pragma unroll 2
  for (int kb = 0; kb < KB; ++kb) {
    bf16x8 AF[4];
    #pragma unroll
    for (int pm = 0; pm < 4; ++pm)
      AF[pm] = *(const bf16x8*)(At + ((pm * KB + kb) * 64 + lane) * 8);
    #pragma unroll
    for (int ff = 0; ff < 2; ++ff) {
      bf16x8 BH[4], BL[4];
      #pragma unroll
      for (int gt = 0; gt < 4; ++gt) {
        BH[gt] = *(const bf16x8*)(bh + (long)ff * 2048 + ((long)kb * 32 + gt) * 512);
        BL[gt] = *(const bf16x8*)(bl + (long)ff * 2048 + ((long)kb * 32 + gt) * 512);
      }
      #pragma unroll
      for (int gt = 0; gt < 4; ++gt) {
        acc[ff][0][gt] = __builtin_amdgcn_mfma_f32_16x16x32_bf16(AF[0], BH[gt], acc[ff][0][gt], 0, 0, 0);
        acc[ff][1][gt] = __builtin_amdgcn_mfma_f32_16x16x32_bf16(AF[1], BH[gt], acc[ff][1][gt], 0, 0, 0);
        acc[ff][0][gt] = __builtin_amdgcn_mfma_f32_16x16x32_bf16(AF[2], BH[gt], acc[ff][0][gt], 0, 0, 0);
        acc[ff][1][gt] = __builtin_amdgcn_mfma_f32_16x16x32_bf16(AF[3], BH[gt], acc[ff][1][gt], 0, 0, 0);
        acc[ff][0][gt] = __builtin_amdgcn_mfma_f32_16x16x32_bf16(AF[0], BL[gt], acc[ff][0][gt], 0, 0, 0);
        acc[ff][1][gt] = __builtin_amdgcn_mfma_f32_16x16x32_bf16(AF[1], BL[gt], acc[ff][1][gt], 0, 0, 0);
      }
    }
  }

  int l15 = lane & 15, lq = lane >> 4;
  #pragma unroll
  for (int ff = 0; ff < 2; ++ff) {
    int f = (fgb + ff) * 16 + l15;
    float bi = bias[f], bff = bias[128 + f], bo = bias[256 + f], bg = bias[384 + f];
    #pragma unroll
    for (int mt = 0; mt < 2; ++mt) {
      #pragma unroll
      for (int r = 0; r < 4; ++r) {
        int m = m0 + mt * 16 + lq * 4 + r;
        float vi = 1.0f / (1.0f + __expf(-(acc[ff][mt][0][r] + bi)));
        float vf = 1.0f / (1.0f + __expf(-(acc[ff][mt][1][r] + bff)));
        float vo = 1.0f / (1.0f + __expf(-(acc[ff][mt][2][r] + bo)));
        float vg = tanhf(acc[ff][mt][3][r] + bg);
        long idx = (long)m * H + f;
        float cn = vf * cbuf[idx] + vi * vg;
        float hn = vo * tanhf(cn);
        cbuf[idx] = cn;
        hbuf[idx] = hn;
        if (out2) {
          int bb = m >> 12, nn = m & (N_NODES - 1);
          __builtin_nontemporal_store(hn,
              &out2[(((long)bb * T + t) * N_NODES + nn) * H + f]);
        }
      }
    }
  }
}

// ---------------- launch ----------------

extern "C" void kernel_launch(void* const* d_in, const int* in_sizes, int n_in,
                              void* d_out, int out_size, void* d_ws, size_t ws_size,
                              hipStream_t stream) {
  const float* x  = (const float*)d_in[0];
  const float* W0 = (const float*)d_in[1];
  const float* b0 = (const float*)d_in[2];
  const float* W1 = (const float*)d_in[3];
  const float* b1 = (const float*)d_in[4];
  const int*   ei = (const int*)d_in[5];
  const int* srcp = ei;
  const int* dstp = ei + N_EDGES;
  float* out = (float*)d_out;

  char* p = (char*)d_ws;
  auto alloc = [&](size_t bytes) {
    char* r = p;
    p += (bytes + 255) & ~(size_t)255;
    return r;
  };
  int*   cnt    = (int*)  alloc(N_NODES * 4);
  int*   fill   = (int*)  alloc(N_NODES * 4);
  float* dinv   = (float*)alloc(N_NODES * 4);
  int*   rowptr = (int*)  alloc((N_NODES + 1) * 4);
  int2*  eg     = (int2*) alloc((size_t)N_EDGES * 8);
  float* hc     = (float*)alloc((size_t)4 * M * H * 4);     // h0,c0,h1,c1 fp32
  unsigned short* Ah  = (unsigned short*)alloc((size_t)M * 256 * 2);
  unsigned short* Al  = (unsigned short*)alloc((size_t)M * 256 * 2);
  unsigned short* Bp0 = (unsigned short*)alloc((size_t)192 * 512 * 2 * 2);
  unsigned short* Bp1 = (unsigned short*)alloc((size_t)256 * 512 * 2 * 2);
  float* h0 = hc;
  float* c0 = hc + (size_t)M * H;
  float* h1 = hc + (size_t)2 * M * H;
  float* c1 = hc + (size_t)3 * M * H;

  hipMemsetAsync(cnt,  0, N_NODES * 4, stream);
  hipMemsetAsync(fill, 0, N_NODES * 4, stream);
  hipMemsetAsync(hc,   0, (size_t)4 * M * H * 4, stream);

  k_count<<<N_EDGES / 256, 256, 0, stream>>>(dstp, cnt);
  k_dinv <<<N_NODES / 256, 256, 0, stream>>>(cnt, dinv);
  k_scan <<<1, 1024, 0, stream>>>(cnt, rowptr);
  k_fill <<<N_EDGES / 256, 256, 0, stream>>>(srcp, dstp, dinv, rowptr, fill, eg);
  k_pack <<<(192 * 64 + 255) / 256, 256, 0, stream>>>(W0, Bp0, 192);
  k_pack <<<(256 * 64 + 255) / 256, 256, 0, stream>>>(W1, Bp1, 256);

  for (int t = 0; t < T; ++t) {
    // layer 0: A = A_hat @ [x_t | h0]   (K = 192), two feature-striped passes
    k_spmm2<64><<<M / 4, 256, 0, stream>>>(rowptr, eg, dinv,
        x + (size_t)t * N_NODES * D_INF, (long)T * N_NODES * D_INF, 0, 192, Ah, Al);
    k_spmm2<128><<<M / 4, 256, 0, stream>>>(rowptr, eg, dinv,
        h0, (long)N_NODES * H, 64, 192, Ah, Al);
    k_gemm_lstm<192><<<1024, 256, 0, stream>>>(Ah, Al, Bp0, b0, h0, c0, nullptr, t);
    // layer 1: A = A_hat @ [h0_t | h1]  (K = 256), two passes
    k_spmm2<128><<<M / 4, 256, 0, stream>>>(rowptr, eg, dinv,
        h0, (long)N_NODES * H, 0, 256, Ah, Al);
    k_spmm2<128><<<M / 4, 256, 0, stream>>>(rowptr, eg, dinv,
        h1, (long)N_NODES * H, 128, 256, Ah, Al);
    k_gemm_lstm<256><<<1024, 256, 0, stream>>>(Ah, Al, Bp1, b1, h1, c1, out, t);
  }
}